// Round 1
// baseline (733.429 us; speedup 1.0000x reference)
//
#include <hip/hip_runtime.h>

#define NNODE 2048
#define NBATCH 32

typedef __attribute__((ext_vector_type(4))) float f32x4;
typedef __attribute__((ext_vector_type(8))) __bf16 bf16x8;

__device__ __forceinline__ void gload16(const void* g, void* lds) {
  __builtin_amdgcn_global_load_lds(
      (const __attribute__((address_space(1))) unsigned int*)g,
      (__attribute__((address_space(3))) unsigned int*)lds, 16, 0, 0);
}

// ---------------------------------------------------------------------------
// Convert f32 -> bf16 (4 elems/thread, exact grid)
__global__ __launch_bounds__(256) void conv_bf16(const float* __restrict__ in,
                                                 __bf16* __restrict__ outp) {
  int i = blockIdx.x * 256 + threadIdx.x;
  float4 q = ((const float4*)in)[i];
  outp[4 * (size_t)i + 0] = (__bf16)q.x;
  outp[4 * (size_t)i + 1] = (__bf16)q.y;
  outp[4 * (size_t)i + 2] = (__bf16)q.z;
  outp[4 * (size_t)i + 3] = (__bf16)q.w;
}

// ---------------------------------------------------------------------------
// A_adp[h][w][v] = softmax_v( relu(E1[w,h,:]·E2[v,h,:]) / 4 ), bf16 out
__global__ __launch_bounds__(256) void adp_softmax(const float* __restrict__ E1,
                                                   const float* __restrict__ E2,
                                                   __bf16* __restrict__ adjh) {
  const int w = blockIdx.x, h = blockIdx.y;
  const int tid = threadIdx.x;
  const int wave = tid >> 6, lane = tid & 63;
  __shared__ float e1s[16];
  __shared__ float sh[8];
  if (tid < 16) e1s[tid] = E1[((size_t)w * 4 + h) * 16 + tid];
  __syncthreads();
  float e1r[16];
#pragma unroll
  for (int c = 0; c < 16; ++c) e1r[c] = e1s[c];

  float sv[8];
  float mx = 0.f;
#pragma unroll
  for (int j = 0; j < 8; ++j) {
    int v = j * 256 + tid;
    const float4* p = (const float4*)(E2 + ((size_t)v * 4 + h) * 16);
    float4 q0 = p[0], q1 = p[1], q2 = p[2], q3 = p[3];
    float d = q0.x * e1r[0] + q0.y * e1r[1] + q0.z * e1r[2] + q0.w * e1r[3]
            + q1.x * e1r[4] + q1.y * e1r[5] + q1.z * e1r[6] + q1.w * e1r[7]
            + q2.x * e1r[8] + q2.y * e1r[9] + q2.z * e1r[10] + q2.w * e1r[11]
            + q3.x * e1r[12] + q3.y * e1r[13] + q3.z * e1r[14] + q3.w * e1r[15];
    d = fmaxf(d, 0.f) * 0.25f;
    sv[j] = d;
    mx = fmaxf(mx, d);
  }
#pragma unroll
  for (int o = 32; o > 0; o >>= 1) mx = fmaxf(mx, __shfl_down(mx, o));
  if (lane == 0) sh[wave] = mx;
  __syncthreads();
  mx = fmaxf(fmaxf(sh[0], sh[1]), fmaxf(sh[2], sh[3]));
  float sum = 0.f;
#pragma unroll
  for (int j = 0; j < 8; ++j) {
    sv[j] = __expf(sv[j] - mx);
    sum += sv[j];
  }
#pragma unroll
  for (int o = 32; o > 0; o >>= 1) sum += __shfl_down(sum, o);
  if (lane == 0) sh[4 + wave] = sum;
  __syncthreads();
  sum = sh[4] + sh[5] + sh[6] + sh[7];
  float inv = 1.f / sum;
#pragma unroll
  for (int j = 0; j < 8; ++j)
    adjh[((size_t)h * NNODE + w) * NNODE + j * 256 + tid] = (__bf16)(sv[j] * inv);
}

// ---------------------------------------------------------------------------
// Wzrt[c][k]=Wz[k][c]*(k<64?s:1); Wzrt[64+c][k]=Wr[k][c]*...; Wct rows 64..127 = 0
__global__ __launch_bounds__(256) void prep_w(const float* __restrict__ Wz,
                                              const float* __restrict__ Wr,
                                              const float* __restrict__ Wc,
                                              const float* __restrict__ wpre,
                                              const float* __restrict__ wadp,
                                              __bf16* __restrict__ Wzrt,
                                              __bf16* __restrict__ Wct) {
  int idx = blockIdx.x * 256 + threadIdx.x;  // 0 .. 128*192-1
  int rr = idx / 192, k = idx % 192;
  float s = 2.f * (*wpre) + (*wadp);
  float sc = (k < 64) ? s : 1.f;
  float vz = (rr < 64) ? Wz[(size_t)k * 64 + rr] : Wr[(size_t)k * 64 + rr - 64];
  Wzrt[idx] = (__bf16)(vz * sc);
  float vc = (rr < 64) ? Wc[(size_t)k * 64 + rr] * sc : 0.f;
  Wct[idx] = (__bf16)vc;
}

// ---------------------------------------------------------------------------
// x f32 [B,N,64] -> XT bf16 [B*64, N] (XT[b*64+c][v]=x[b,v,c]) and xbf bf16 [B*N,64]
__global__ __launch_bounds__(256) void transpose_x(const float* __restrict__ x,
                                                   __bf16* __restrict__ XT,
                                                   __bf16* __restrict__ xbf) {
  const int b = blockIdx.y, v0 = blockIdx.x * 64;
  const int tid = threadIdx.x;
  __shared__ float t[64][65];
  const int vr = tid >> 2, c0 = (tid & 3) * 16;
  const float* src = x + ((size_t)b * NNODE + v0 + vr) * 64 + c0;
  __bf16* xb = xbf + ((size_t)b * NNODE + v0 + vr) * 64 + c0;
#pragma unroll
  for (int j = 0; j < 4; ++j) {
    float4 q = ((const float4*)src)[j];
    t[vr][c0 + j * 4 + 0] = q.x;
    t[vr][c0 + j * 4 + 1] = q.y;
    t[vr][c0 + j * 4 + 2] = q.z;
    t[vr][c0 + j * 4 + 3] = q.w;
    xb[j * 4 + 0] = (__bf16)q.x;
    xb[j * 4 + 1] = (__bf16)q.y;
    xb[j * 4 + 2] = (__bf16)q.z;
    xb[j * 4 + 3] = (__bf16)q.w;
  }
  __syncthreads();
#pragma unroll
  for (int jr = 0; jr < 16; ++jr) {
    int c = jr * 4 + (tid >> 6);
    int v = tid & 63;
    XT[((size_t)b * 64 + c) * NNODE + v0 + v] = (__bf16)t[v][c];
  }
}

// rx bf16 [B*N,64] -> XT bf16 [B*64, N]
__global__ __launch_bounds__(256) void transpose_rx(const __bf16* __restrict__ rx,
                                                    __bf16* __restrict__ XT) {
  const int b = blockIdx.y, v0 = blockIdx.x * 64;
  const int tid = threadIdx.x;
  __shared__ float t[64][65];
  const int vr = tid >> 2, c0 = (tid & 3) * 16;
  const __bf16* src = rx + ((size_t)b * NNODE + v0 + vr) * 64 + c0;
  bf16x8 q0 = ((const bf16x8*)src)[0];
  bf16x8 q1 = ((const bf16x8*)src)[1];
#pragma unroll
  for (int i = 0; i < 8; ++i) {
    t[vr][c0 + i] = (float)q0[i];
    t[vr][c0 + 8 + i] = (float)q1[i];
  }
  __syncthreads();
#pragma unroll
  for (int jr = 0; jr < 16; ++jr) {
    int c = jr * 4 + (tid >> 6);
    int v = tid & 63;
    XT[((size_t)b * 64 + c) * NNODE + v0 + v] = (__bf16)t[v][c];
  }
}

// ---------------------------------------------------------------------------
// m97-structure GEMM, batched over z:
//   C_z[m][n] = sum_k A_z[m][k] * Bt_z[n][k]   (all 2048x2048 bf16 row-major)
__global__ __launch_bounds__(256) void gemm_hop(const __bf16* __restrict__ Abase,
                                                size_t aStrideZ,
                                                const __bf16* __restrict__ BtBase,
                                                __bf16* __restrict__ Cbase) {
  __shared__ __bf16 As[128 * 32];
  __shared__ __bf16 Bs[128 * 32];
  const int tid = threadIdx.x;
  const int wave = tid >> 6, lane = tid & 63;
  const int wr = wave >> 1, wc = wave & 1;
  const size_t z = blockIdx.z;
  const int m0 = blockIdx.x * 128, n0 = blockIdx.y * 128;
  const __bf16* A = Abase + z * aStrideZ;
  const __bf16* Bt = BtBase + z * (size_t)(NNODE * NNODE);
  __bf16* C = Cbase + z * (size_t)(NNODE * NNODE);

  const int rowA = tid >> 2;
  const int colb = (tid & 3) * 16;  // byte offset within 64B k-chunk
  const char* aS0 = (const char*)(A + (size_t)(m0 + rowA) * NNODE) + colb;
  const char* aS1 = (const char*)(A + (size_t)(m0 + rowA + 64) * NNODE) + colb;
  const char* bS0 = (const char*)(Bt + (size_t)(n0 + rowA) * NNODE) + colb;
  const char* bS1 = (const char*)(Bt + (size_t)(n0 + rowA + 64) * NNODE) + colb;
  char* asD0 = (char*)As + wave * 1024;
  char* asD1 = (char*)As + 4096 + wave * 1024;
  char* bsD0 = (char*)Bs + wave * 1024;
  char* bsD1 = (char*)Bs + 4096 + wave * 1024;

  f32x4 acc[4][4] = {};

  for (int kt = 0; kt < NNODE / 32; ++kt) {
    gload16(aS0, asD0);
    gload16(aS1, asD1);
    gload16(bS0, bsD0);
    gload16(bS1, bsD1);
    aS0 += 64; aS1 += 64; bS0 += 64; bS1 += 64;
    __syncthreads();
    bf16x8 af[4], bfr[4];
#pragma unroll
    for (int mi = 0; mi < 4; ++mi)
      af[mi] = *(const bf16x8*)((const char*)As +
               ((wr * 64 + mi * 16 + (lane & 15)) * 64 + (lane >> 4) * 16));
#pragma unroll
    for (int ni = 0; ni < 4; ++ni)
      bfr[ni] = *(const bf16x8*)((const char*)Bs +
               ((wc * 64 + ni * 16 + (lane & 15)) * 64 + (lane >> 4) * 16));
#pragma unroll
    for (int mi = 0; mi < 4; ++mi)
#pragma unroll
      for (int ni = 0; ni < 4; ++ni)
        acc[mi][ni] = __builtin_amdgcn_mfma_f32_16x16x32_bf16(af[mi], bfr[ni],
                                                              acc[mi][ni], 0, 0, 0);
    __syncthreads();
  }

  const int crow = (lane >> 4) * 4;
  const int ccol = lane & 15;
#pragma unroll
  for (int mi = 0; mi < 4; ++mi)
#pragma unroll
    for (int ni = 0; ni < 4; ++ni) {
      int r0 = m0 + wr * 64 + mi * 16 + crow;
      int cc = n0 + wc * 64 + ni * 16 + ccol;
#pragma unroll
      for (int r = 0; r < 4; ++r)
        C[(size_t)(r0 + r) * NNODE + cc] = (__bf16)acc[mi][ni][r];
    }
}

// ---------------------------------------------------------------------------
// S1[(b,w),c] = sum_z wz * H1[z][b*64+c][w] ;  same for S2/H2.  bf16 out [B*N,64]
__global__ __launch_bounds__(256) void combine_s(const __bf16* __restrict__ H1,
                                                 const __bf16* __restrict__ H2,
                                                 __bf16* __restrict__ S1,
                                                 __bf16* __restrict__ S2,
                                                 const float* __restrict__ wpre,
                                                 const float* __restrict__ wadp) {
  const int b = blockIdx.y;
  const int w0 = blockIdx.x * 64;
  const int tid = threadIdx.x;
  const float wp = *wpre, wa = *wadp * 0.25f;
  __shared__ float t1[64][65];
  __shared__ float t2[64][65];
  const int cr = tid >> 2;
  const int wg = (tid & 3) * 16;
  float a1[16] = {}, a2[16] = {};
  const size_t NN2 = (size_t)NNODE * NNODE;
#pragma unroll
  for (int z = 0; z < 6; ++z) {
    float wz = (z < 2) ? wp : wa;
    const __bf16* p1 = H1 + z * NN2 + (size_t)(b * 64 + cr) * NNODE + w0 + wg;
    const __bf16* p2 = H2 + z * NN2 + (size_t)(b * 64 + cr) * NNODE + w0 + wg;
    bf16x8 q10 = ((const bf16x8*)p1)[0], q11 = ((const bf16x8*)p1)[1];
    bf16x8 q20 = ((const bf16x8*)p2)[0], q21 = ((const bf16x8*)p2)[1];
#pragma unroll
    for (int i = 0; i < 8; ++i) {
      a1[i] += wz * (float)q10[i];
      a1[8 + i] += wz * (float)q11[i];
      a2[i] += wz * (float)q20[i];
      a2[8 + i] += wz * (float)q21[i];
    }
  }
#pragma unroll
  for (int i = 0; i < 16; ++i) {
    t1[cr][wg + i] = a1[i];
    t2[cr][wg + i] = a2[i];
  }
  __syncthreads();
#pragma unroll
  for (int jr = 0; jr < 16; ++jr) {
    int wl = jr * 4 + (tid >> 6);
    int c = tid & 63;
    size_t o = ((size_t)b * NNODE + w0 + wl) * 64 + c;
    S1[o] = (__bf16)t1[c][wl];
    S2[o] = (__bf16)t2[c][wl];
  }
}

// ---------------------------------------------------------------------------
// Gate linear GEMM: [65536 x 192] @ Wt^T, K=192, N=128, fused epilogues.
// MODE 0: cols 0-63 -> z=sigmoid -> zbuf(f32); cols 64-127 -> r -> rx=(bf16)(r*hid)
// MODE 1: cols 0-63 -> c=tanh   -> out=(1-z)*hid+z*c (f32)
template <int MODE>
__global__ __launch_bounds__(256) void gemm_lin(const __bf16* __restrict__ Xp,
                                                const __bf16* __restrict__ S1,
                                                const __bf16* __restrict__ S2,
                                                const __bf16* __restrict__ Wt,
                                                const float* __restrict__ b0,
                                                const float* __restrict__ b1,
                                                const float* __restrict__ wpre,
                                                const float* __restrict__ wadp,
                                                const float* __restrict__ hid,
                                                float* __restrict__ zbuf,
                                                __bf16* __restrict__ rxout,
                                                float* __restrict__ outp) {
  __shared__ __bf16 As[128 * 32];
  __shared__ __bf16 Bs[128 * 32];
  const int tid = threadIdx.x;
  const int wave = tid >> 6, lane = tid & 63;
  const int wr = wave >> 1, wc = wave & 1;
  const int m0 = blockIdx.x * 128;
  const int rowA = tid >> 2;
  const int colb = (tid & 3) * 16;
  const __bf16* srcs[3] = {Xp, S1, S2};
  char* asD0 = (char*)As + wave * 1024;
  char* asD1 = (char*)As + 4096 + wave * 1024;
  char* bsD0 = (char*)Bs + wave * 1024;
  char* bsD1 = (char*)Bs + 4096 + wave * 1024;

  f32x4 acc[4][4] = {};

#pragma unroll
  for (int kt = 0; kt < 6; ++kt) {
    const __bf16* Ab = srcs[kt >> 1];
    const char* aS0 = (const char*)(Ab + (size_t)(m0 + rowA) * 64) + (kt & 1) * 64 + colb;
    const char* aS1 = (const char*)(Ab + (size_t)(m0 + rowA + 64) * 64) + (kt & 1) * 64 + colb;
    const char* bS0 = (const char*)(Wt + (size_t)rowA * 192) + kt * 64 + colb;
    const char* bS1 = (const char*)(Wt + (size_t)(rowA + 64) * 192) + kt * 64 + colb;
    gload16(aS0, asD0);
    gload16(aS1, asD1);
    gload16(bS0, bsD0);
    gload16(bS1, bsD1);
    __syncthreads();
    bf16x8 af[4], bfr[4];
#pragma unroll
    for (int mi = 0; mi < 4; ++mi)
      af[mi] = *(const bf16x8*)((const char*)As +
               ((wr * 64 + mi * 16 + (lane & 15)) * 64 + (lane >> 4) * 16));
#pragma unroll
    for (int ni = 0; ni < 4; ++ni)
      bfr[ni] = *(const bf16x8*)((const char*)Bs +
               ((wc * 64 + ni * 16 + (lane & 15)) * 64 + (lane >> 4) * 16));
#pragma unroll
    for (int mi = 0; mi < 4; ++mi)
#pragma unroll
      for (int ni = 0; ni < 4; ++ni)
        acc[mi][ni] = __builtin_amdgcn_mfma_f32_16x16x32_bf16(af[mi], bfr[ni],
                                                              acc[mi][ni], 0, 0, 0);
    __syncthreads();
  }

  const float wp = *wpre, wa = *wadp;
  const float s = 2.f * wp + wa;
  const int crow = (lane >> 4) * 4;
  const int ccol = lane & 15;
#pragma unroll
  for (int mi = 0; mi < 4; ++mi)
#pragma unroll
    for (int ni = 0; ni < 4; ++ni) {
      int r0 = m0 + wr * 64 + mi * 16 + crow;
      int col = wc * 64 + ni * 16 + ccol;
      int cf = col & 63;
#pragma unroll
      for (int r = 0; r < 4; ++r) {
        int row = r0 + r;
        float g = acc[mi][ni][r];
        if (MODE == 0) {
          if (col < 64) {
            g += s * b0[cf];
            zbuf[(size_t)row * 64 + cf] = 1.f / (1.f + __expf(-g));
          } else {
            g += s * b1[cf];
            float rv = 1.f / (1.f + __expf(-g));
            rxout[(size_t)row * 64 + cf] = (__bf16)(rv * hid[(size_t)row * 64 + cf]);
          }
        } else {
          if (col < 64) {
            g += s * b0[cf];
            float cv = 1.f - 2.f / (1.f + __expf(2.f * g));
            float zv = zbuf[(size_t)row * 64 + cf];
            float hv = hid[(size_t)row * 64 + cf];
            outp[(size_t)row * 64 + cf] = (1.f - zv) * hv + zv * cv;
          }
        }
      }
    }
}

// ---------------------------------------------------------------------------
extern "C" void kernel_launch(void* const* d_in, const int* in_sizes, int n_in,
                              void* d_out, int out_size, void* d_ws, size_t ws_size,
                              hipStream_t stream) {
  (void)in_sizes; (void)n_in; (void)out_size;
  const float* x    = (const float*)d_in[0];
  const float* A1   = (const float*)d_in[1];
  const float* A2   = (const float*)d_in[2];
  const float* E1   = (const float*)d_in[3];
  const float* E2   = (const float*)d_in[4];
  const float* Wz   = (const float*)d_in[5];
  const float* bz   = (const float*)d_in[6];
  const float* Wr   = (const float*)d_in[7];
  const float* br   = (const float*)d_in[8];
  const float* Wc   = (const float*)d_in[9];
  const float* bc   = (const float*)d_in[10];
  const float* wpre = (const float*)d_in[11];
  const float* wadp = (const float*)d_in[12];
  float* out = (float*)d_out;

  char* ws = (char*)d_ws;
  const size_t NN2 = (size_t)NNODE * NNODE;  // 4,194,304 (= B*N*D too)
  __bf16* ADJ  = (__bf16*)(ws);                    // 6*NN2 bf16
  __bf16* XT   = (__bf16*)(ws + 6  * NN2 * 2);     // NN2
  __bf16* H1   = (__bf16*)(ws + 7  * NN2 * 2);     // 6*NN2
  __bf16* H2   = (__bf16*)(ws + 13 * NN2 * 2);     // 6*NN2
  __bf16* xbf  = (__bf16*)(ws + 19 * NN2 * 2);     // NN2
  __bf16* rx   = (__bf16*)(ws + 20 * NN2 * 2);     // NN2
  __bf16* S1   = (__bf16*)(ws + 21 * NN2 * 2);     // NN2
  __bf16* S2   = (__bf16*)(ws + 22 * NN2 * 2);     // NN2
  float*  zbuf = (float*)(ws + 23 * NN2 * 2);      // NN2 f32
  __bf16* Wzrt = (__bf16*)(ws + 23 * NN2 * 2 + NN2 * 4);
  __bf16* Wct  = (__bf16*)(ws + 23 * NN2 * 2 + NN2 * 4 + 128 * 192 * 2);
  if (ws_size < 23 * NN2 * 2 + NN2 * 4 + 2 * 128 * 192 * 2) return;

  conv_bf16<<<4096, 256, 0, stream>>>(A1, ADJ);
  conv_bf16<<<4096, 256, 0, stream>>>(A2, ADJ + NN2);
  adp_softmax<<<dim3(NNODE, 4), 256, 0, stream>>>(E1, E2, ADJ + 2 * NN2);
  prep_w<<<96, 256, 0, stream>>>(Wz, Wr, Wc, wpre, wadp, Wzrt, Wct);
  transpose_x<<<dim3(32, 32), 256, 0, stream>>>(x, XT, xbf);

  // stage 1: hops on x (shared by z and r gates)
  gemm_hop<<<dim3(16, 16, 6), 256, 0, stream>>>(XT, 0, ADJ, H1);
  gemm_hop<<<dim3(16, 16, 6), 256, 0, stream>>>(H1, NN2, ADJ, H2);
  combine_s<<<dim3(32, 32), 256, 0, stream>>>(H1, H2, S1, S2, wpre, wadp);
  gemm_lin<0><<<512, 256, 0, stream>>>(xbf, S1, S2, Wzrt, bz, br, wpre, wadp,
                                       x, zbuf, rx, nullptr);

  // stage 2: hops on r*x
  transpose_rx<<<dim3(32, 32), 256, 0, stream>>>(rx, XT);
  gemm_hop<<<dim3(16, 16, 6), 256, 0, stream>>>(XT, 0, ADJ, H1);
  gemm_hop<<<dim3(16, 16, 6), 256, 0, stream>>>(H1, NN2, ADJ, H2);
  combine_s<<<dim3(32, 32), 256, 0, stream>>>(H1, H2, S1, S2, wpre, wadp);
  gemm_lin<1><<<512, 256, 0, stream>>>(rx, S1, S2, Wct, bc, nullptr, wpre, wadp,
                                       x, zbuf, nullptr, out);
}

// Round 2
// 599.410 us; speedup vs baseline: 1.2236x; 1.2236x over previous
//
#include <hip/hip_runtime.h>

#define NNODE 2048
#define NBATCH 32

typedef __attribute__((ext_vector_type(4))) float f32x4;
typedef __attribute__((ext_vector_type(8))) __bf16 bf16x8;

__device__ __forceinline__ void gload16(const void* g, void* lds) {
  __builtin_amdgcn_global_load_lds(
      (const __attribute__((address_space(1))) unsigned int*)g,
      (__attribute__((address_space(3))) unsigned int*)lds, 16, 0, 0);
}

// ---------------------------------------------------------------------------
// Convert f32 -> bf16 (4 elems/thread, exact grid)
__global__ __launch_bounds__(256) void conv_bf16(const float* __restrict__ in,
                                                 __bf16* __restrict__ outp) {
  int i = blockIdx.x * 256 + threadIdx.x;
  float4 q = ((const float4*)in)[i];
  outp[4 * (size_t)i + 0] = (__bf16)q.x;
  outp[4 * (size_t)i + 1] = (__bf16)q.y;
  outp[4 * (size_t)i + 2] = (__bf16)q.z;
  outp[4 * (size_t)i + 3] = (__bf16)q.w;
}

// ---------------------------------------------------------------------------
// Repack E1,E2 [N,H,16] f32 -> [H][N][32] bf16 (K zero-padded 16->32)
__global__ __launch_bounds__(256) void prep_e(const float* __restrict__ E1,
                                              const float* __restrict__ E2,
                                              __bf16* __restrict__ E1p,
                                              __bf16* __restrict__ E2p) {
  int idx = blockIdx.x * 256 + threadIdx.x;  // 0..32767
  int cq = idx & 3;
  int n = (idx >> 2) & 2047;
  int h = idx >> 13;
  const float4 q1 = *(const float4*)(E1 + (size_t)(n * 4 + h) * 16 + cq * 4);
  const float4 q2 = *(const float4*)(E2 + (size_t)(n * 4 + h) * 16 + cq * 4);
  size_t o = ((size_t)h * NNODE + n) * 32 + cq * 4;
  E1p[o + 0] = (__bf16)q1.x; E1p[o + 1] = (__bf16)q1.y;
  E1p[o + 2] = (__bf16)q1.z; E1p[o + 3] = (__bf16)q1.w;
  E2p[o + 0] = (__bf16)q2.x; E2p[o + 1] = (__bf16)q2.y;
  E2p[o + 2] = (__bf16)q2.z; E2p[o + 3] = (__bf16)q2.w;
  size_t oz = o + 16;
  E1p[oz + 0] = (__bf16)0.f; E1p[oz + 1] = (__bf16)0.f;
  E1p[oz + 2] = (__bf16)0.f; E1p[oz + 3] = (__bf16)0.f;
  E2p[oz + 0] = (__bf16)0.f; E2p[oz + 1] = (__bf16)0.f;
  E2p[oz + 2] = (__bf16)0.f; E2p[oz + 3] = (__bf16)0.f;
}

// ---------------------------------------------------------------------------
// SC[h][w][v] = relu(E1p_h @ E2p_h^T)/4, bf16. Single K=32 MFMA step.
__global__ __launch_bounds__(256) void score_gemm(const __bf16* __restrict__ E1p,
                                                  const __bf16* __restrict__ E2p,
                                                  __bf16* __restrict__ SC) {
  __shared__ __bf16 As[128 * 32];
  __shared__ __bf16 Bs[128 * 32];
  const int tid = threadIdx.x;
  const int wave = tid >> 6, lane = tid & 63;
  const int wr = wave >> 1, wc = wave & 1;
  const int h = blockIdx.z;
  const int m0 = blockIdx.x * 128, n0 = blockIdx.y * 128;
  const __bf16* A = E1p + (size_t)h * NNODE * 32;
  const __bf16* Bt = E2p + (size_t)h * NNODE * 32;
  const int rowA = tid >> 2;
  const int colb = (tid & 3) * 16;
  gload16((const char*)(A + (size_t)(m0 + rowA) * 32) + colb, (char*)As + wave * 1024);
  gload16((const char*)(A + (size_t)(m0 + rowA + 64) * 32) + colb, (char*)As + 4096 + wave * 1024);
  gload16((const char*)(Bt + (size_t)(n0 + rowA) * 32) + colb, (char*)Bs + wave * 1024);
  gload16((const char*)(Bt + (size_t)(n0 + rowA + 64) * 32) + colb, (char*)Bs + 4096 + wave * 1024);
  __syncthreads();

  f32x4 acc[4][4] = {};
  bf16x8 af[4], bfr[4];
#pragma unroll
  for (int mi = 0; mi < 4; ++mi)
    af[mi] = *(const bf16x8*)((const char*)As +
             ((wr * 64 + mi * 16 + (lane & 15)) * 64 + (lane >> 4) * 16));
#pragma unroll
  for (int ni = 0; ni < 4; ++ni)
    bfr[ni] = *(const bf16x8*)((const char*)Bs +
             ((wc * 64 + ni * 16 + (lane & 15)) * 64 + (lane >> 4) * 16));
#pragma unroll
  for (int mi = 0; mi < 4; ++mi)
#pragma unroll
    for (int ni = 0; ni < 4; ++ni)
      acc[mi][ni] = __builtin_amdgcn_mfma_f32_16x16x32_bf16(af[mi], bfr[ni],
                                                            acc[mi][ni], 0, 0, 0);

  const int crow = (lane >> 4) * 4;
  const int ccol = lane & 15;
#pragma unroll
  for (int mi = 0; mi < 4; ++mi)
#pragma unroll
    for (int ni = 0; ni < 4; ++ni) {
      int r0 = m0 + wr * 64 + mi * 16 + crow;
      int cc = n0 + wc * 64 + ni * 16 + ccol;
#pragma unroll
      for (int r = 0; r < 4; ++r) {
        float val = fmaxf(acc[mi][ni][r], 0.f) * 0.25f;
        SC[((size_t)h * NNODE + r0 + r) * NNODE + cc] = (__bf16)val;
      }
    }
}

// ---------------------------------------------------------------------------
// Row softmax over v: one wave per row of SC [8192 x 2048] bf16 -> adjh bf16
__global__ __launch_bounds__(256) void softmax_rows(const __bf16* __restrict__ SC,
                                                    __bf16* __restrict__ adjh) {
  const int tid = threadIdx.x;
  const int wave = tid >> 6, lane = tid & 63;
  const size_t row = (size_t)blockIdx.x * 4 + wave;
  const __bf16* src = SC + row * NNODE;
  __bf16* dst = adjh + row * NNODE;
  float v[32];
  float mx = 0.f;
#pragma unroll
  for (int j = 0; j < 4; ++j) {
    bf16x8 q = *(const bf16x8*)(src + j * 512 + lane * 8);
#pragma unroll
    for (int i = 0; i < 8; ++i) {
      float f = (float)q[i];
      v[j * 8 + i] = f;
      mx = fmaxf(mx, f);
    }
  }
#pragma unroll
  for (int o = 32; o > 0; o >>= 1) mx = fmaxf(mx, __shfl_xor(mx, o));
  float s = 0.f;
#pragma unroll
  for (int i = 0; i < 32; ++i) {
    v[i] = __expf(v[i] - mx);
    s += v[i];
  }
#pragma unroll
  for (int o = 32; o > 0; o >>= 1) s += __shfl_xor(s, o);
  float inv = 1.f / s;
#pragma unroll
  for (int j = 0; j < 4; ++j) {
    bf16x8 q;
#pragma unroll
    for (int i = 0; i < 8; ++i) q[i] = (__bf16)(v[j * 8 + i] * inv);
    *(bf16x8*)(dst + j * 512 + lane * 8) = q;
  }
}

// ---------------------------------------------------------------------------
// Wzrt[c][k]=Wz[k][c]*(k<64?s:1); Wzrt[64+c][k]=Wr[k][c]*...; Wct rows 64..127 = 0
__global__ __launch_bounds__(256) void prep_w(const float* __restrict__ Wz,
                                              const float* __restrict__ Wr,
                                              const float* __restrict__ Wc,
                                              const float* __restrict__ wpre,
                                              const float* __restrict__ wadp,
                                              __bf16* __restrict__ Wzrt,
                                              __bf16* __restrict__ Wct) {
  int idx = blockIdx.x * 256 + threadIdx.x;  // 0 .. 128*192-1
  int rr = idx / 192, k = idx % 192;
  float s = 2.f * (*wpre) + (*wadp);
  float sc = (k < 64) ? s : 1.f;
  float vz = (rr < 64) ? Wz[(size_t)k * 64 + rr] : Wr[(size_t)k * 64 + rr - 64];
  Wzrt[idx] = (__bf16)(vz * sc);
  float vc = (rr < 64) ? Wc[(size_t)k * 64 + rr] * sc : 0.f;
  Wct[idx] = (__bf16)vc;
}

// ---------------------------------------------------------------------------
// x f32 [B,N,64] -> XT bf16 [B*64, N] (XT[b*64+c][v]=x[b,v,c]) and xbf bf16 [B*N,64]
__global__ __launch_bounds__(256) void transpose_x(const float* __restrict__ x,
                                                   __bf16* __restrict__ XT,
                                                   __bf16* __restrict__ xbf) {
  const int b = blockIdx.y, v0 = blockIdx.x * 64;
  const int tid = threadIdx.x;
  __shared__ float t[64][65];
  const int vr = tid >> 2, c0 = (tid & 3) * 16;
  const float* src = x + ((size_t)b * NNODE + v0 + vr) * 64 + c0;
  __bf16* xb = xbf + ((size_t)b * NNODE + v0 + vr) * 64 + c0;
#pragma unroll
  for (int j = 0; j < 4; ++j) {
    float4 q = ((const float4*)src)[j];
    t[vr][c0 + j * 4 + 0] = q.x;
    t[vr][c0 + j * 4 + 1] = q.y;
    t[vr][c0 + j * 4 + 2] = q.z;
    t[vr][c0 + j * 4 + 3] = q.w;
    xb[j * 4 + 0] = (__bf16)q.x;
    xb[j * 4 + 1] = (__bf16)q.y;
    xb[j * 4 + 2] = (__bf16)q.z;
    xb[j * 4 + 3] = (__bf16)q.w;
  }
  __syncthreads();
#pragma unroll
  for (int jr = 0; jr < 16; ++jr) {
    int c = jr * 4 + (tid >> 6);
    int v = tid & 63;
    XT[((size_t)b * 64 + c) * NNODE + v0 + v] = (__bf16)t[v][c];
  }
}

// rx bf16 [B*N,64] -> XT bf16 [B*64, N]
__global__ __launch_bounds__(256) void transpose_rx(const __bf16* __restrict__ rx,
                                                    __bf16* __restrict__ XT) {
  const int b = blockIdx.y, v0 = blockIdx.x * 64;
  const int tid = threadIdx.x;
  __shared__ float t[64][65];
  const int vr = tid >> 2, c0 = (tid & 3) * 16;
  const __bf16* src = rx + ((size_t)b * NNODE + v0 + vr) * 64 + c0;
  bf16x8 q0 = ((const bf16x8*)src)[0];
  bf16x8 q1 = ((const bf16x8*)src)[1];
#pragma unroll
  for (int i = 0; i < 8; ++i) {
    t[vr][c0 + i] = (float)q0[i];
    t[vr][c0 + 8 + i] = (float)q1[i];
  }
  __syncthreads();
#pragma unroll
  for (int jr = 0; jr < 16; ++jr) {
    int c = jr * 4 + (tid >> 6);
    int v = tid & 63;
    XT[((size_t)b * 64 + c) * NNODE + v0 + v] = (__bf16)t[v][c];
  }
}

// ---------------------------------------------------------------------------
// m97-structure GEMM, batched over z:
//   C_z[m][n] = sum_k A_z[m][k] * Bt_z[n][k]   (all 2048x2048 bf16 row-major)
__global__ __launch_bounds__(256) void gemm_hop(const __bf16* __restrict__ Abase,
                                                size_t aStrideZ,
                                                const __bf16* __restrict__ BtBase,
                                                __bf16* __restrict__ Cbase) {
  __shared__ __bf16 As[128 * 32];
  __shared__ __bf16 Bs[128 * 32];
  const int tid = threadIdx.x;
  const int wave = tid >> 6, lane = tid & 63;
  const int wr = wave >> 1, wc = wave & 1;
  const size_t z = blockIdx.z;
  const int m0 = blockIdx.x * 128, n0 = blockIdx.y * 128;
  const __bf16* A = Abase + z * aStrideZ;
  const __bf16* Bt = BtBase + z * (size_t)(NNODE * NNODE);
  __bf16* C = Cbase + z * (size_t)(NNODE * NNODE);

  const int rowA = tid >> 2;
  const int colb = (tid & 3) * 16;  // byte offset within 64B k-chunk
  const char* aS0 = (const char*)(A + (size_t)(m0 + rowA) * NNODE) + colb;
  const char* aS1 = (const char*)(A + (size_t)(m0 + rowA + 64) * NNODE) + colb;
  const char* bS0 = (const char*)(Bt + (size_t)(n0 + rowA) * NNODE) + colb;
  const char* bS1 = (const char*)(Bt + (size_t)(n0 + rowA + 64) * NNODE) + colb;
  char* asD0 = (char*)As + wave * 1024;
  char* asD1 = (char*)As + 4096 + wave * 1024;
  char* bsD0 = (char*)Bs + wave * 1024;
  char* bsD1 = (char*)Bs + 4096 + wave * 1024;

  f32x4 acc[4][4] = {};

  for (int kt = 0; kt < NNODE / 32; ++kt) {
    gload16(aS0, asD0);
    gload16(aS1, asD1);
    gload16(bS0, bsD0);
    gload16(bS1, bsD1);
    aS0 += 64; aS1 += 64; bS0 += 64; bS1 += 64;
    __syncthreads();
    bf16x8 af[4], bfr[4];
#pragma unroll
    for (int mi = 0; mi < 4; ++mi)
      af[mi] = *(const bf16x8*)((const char*)As +
               ((wr * 64 + mi * 16 + (lane & 15)) * 64 + (lane >> 4) * 16));
#pragma unroll
    for (int ni = 0; ni < 4; ++ni)
      bfr[ni] = *(const bf16x8*)((const char*)Bs +
               ((wc * 64 + ni * 16 + (lane & 15)) * 64 + (lane >> 4) * 16));
#pragma unroll
    for (int mi = 0; mi < 4; ++mi)
#pragma unroll
      for (int ni = 0; ni < 4; ++ni)
        acc[mi][ni] = __builtin_amdgcn_mfma_f32_16x16x32_bf16(af[mi], bfr[ni],
                                                              acc[mi][ni], 0, 0, 0);
    __syncthreads();
  }

  const int crow = (lane >> 4) * 4;
  const int ccol = lane & 15;
#pragma unroll
  for (int mi = 0; mi < 4; ++mi)
#pragma unroll
    for (int ni = 0; ni < 4; ++ni) {
      int r0 = m0 + wr * 64 + mi * 16 + crow;
      int cc = n0 + wc * 64 + ni * 16 + ccol;
#pragma unroll
      for (int r = 0; r < 4; ++r)
        C[(size_t)(r0 + r) * NNODE + cc] = (__bf16)acc[mi][ni][r];
    }
}

// ---------------------------------------------------------------------------
// S1[(b,w),c] = sum_z wz * H1[z][b*64+c][w] ;  same for S2/H2.  bf16 out [B*N,64]
__global__ __launch_bounds__(256) void combine_s(const __bf16* __restrict__ H1,
                                                 const __bf16* __restrict__ H2,
                                                 __bf16* __restrict__ S1,
                                                 __bf16* __restrict__ S2,
                                                 const float* __restrict__ wpre,
                                                 const float* __restrict__ wadp) {
  const int b = blockIdx.y;
  const int w0 = blockIdx.x * 64;
  const int tid = threadIdx.x;
  const float wp = *wpre, wa = *wadp * 0.25f;
  __shared__ float t1[64][65];
  __shared__ float t2[64][65];
  const int cr = tid >> 2;
  const int wg = (tid & 3) * 16;
  float a1[16] = {}, a2[16] = {};
  const size_t NN2 = (size_t)NNODE * NNODE;
#pragma unroll
  for (int z = 0; z < 6; ++z) {
    float wz = (z < 2) ? wp : wa;
    const __bf16* p1 = H1 + z * NN2 + (size_t)(b * 64 + cr) * NNODE + w0 + wg;
    const __bf16* p2 = H2 + z * NN2 + (size_t)(b * 64 + cr) * NNODE + w0 + wg;
    bf16x8 q10 = ((const bf16x8*)p1)[0], q11 = ((const bf16x8*)p1)[1];
    bf16x8 q20 = ((const bf16x8*)p2)[0], q21 = ((const bf16x8*)p2)[1];
#pragma unroll
    for (int i = 0; i < 8; ++i) {
      a1[i] += wz * (float)q10[i];
      a1[8 + i] += wz * (float)q11[i];
      a2[i] += wz * (float)q20[i];
      a2[8 + i] += wz * (float)q21[i];
    }
  }
#pragma unroll
  for (int i = 0; i < 16; ++i) {
    t1[cr][wg + i] = a1[i];
    t2[cr][wg + i] = a2[i];
  }
  __syncthreads();
#pragma unroll
  for (int jr = 0; jr < 16; ++jr) {
    int wl = jr * 4 + (tid >> 6);
    int c = tid & 63;
    size_t o = ((size_t)b * NNODE + w0 + wl) * 64 + c;
    S1[o] = (__bf16)t1[c][wl];
    S2[o] = (__bf16)t2[c][wl];
  }
}

// ---------------------------------------------------------------------------
// Gate linear GEMM: [65536 x 192] @ Wt^T, K=192, N=128, fused epilogues.
// MODE 0: cols 0-63 -> z=sigmoid -> zbuf(f32); cols 64-127 -> r -> rx=(bf16)(r*hid)
// MODE 1: cols 0-63 -> c=tanh   -> out=(1-z)*hid+z*c (f32)
template <int MODE>
__global__ __launch_bounds__(256) void gemm_lin(const __bf16* __restrict__ Xp,
                                                const __bf16* __restrict__ S1,
                                                const __bf16* __restrict__ S2,
                                                const __bf16* __restrict__ Wt,
                                                const float* __restrict__ b0,
                                                const float* __restrict__ b1,
                                                const float* __restrict__ wpre,
                                                const float* __restrict__ wadp,
                                                const float* __restrict__ hid,
                                                float* __restrict__ zbuf,
                                                __bf16* __restrict__ rxout,
                                                float* __restrict__ outp) {
  __shared__ __bf16 As[128 * 32];
  __shared__ __bf16 Bs[128 * 32];
  const int tid = threadIdx.x;
  const int wave = tid >> 6, lane = tid & 63;
  const int wr = wave >> 1, wc = wave & 1;
  const int m0 = blockIdx.x * 128;
  const int rowA = tid >> 2;
  const int colb = (tid & 3) * 16;
  const __bf16* srcs[3] = {Xp, S1, S2};
  char* asD0 = (char*)As + wave * 1024;
  char* asD1 = (char*)As + 4096 + wave * 1024;
  char* bsD0 = (char*)Bs + wave * 1024;
  char* bsD1 = (char*)Bs + 4096 + wave * 1024;

  f32x4 acc[4][4] = {};

#pragma unroll
  for (int kt = 0; kt < 6; ++kt) {
    const __bf16* Ab = srcs[kt >> 1];
    const char* aS0 = (const char*)(Ab + (size_t)(m0 + rowA) * 64) + (kt & 1) * 64 + colb;
    const char* aS1 = (const char*)(Ab + (size_t)(m0 + rowA + 64) * 64) + (kt & 1) * 64 + colb;
    const char* bS0 = (const char*)(Wt + (size_t)rowA * 192) + kt * 64 + colb;
    const char* bS1 = (const char*)(Wt + (size_t)(rowA + 64) * 192) + kt * 64 + colb;
    gload16(aS0, asD0);
    gload16(aS1, asD1);
    gload16(bS0, bsD0);
    gload16(bS1, bsD1);
    __syncthreads();
    bf16x8 af[4], bfr[4];
#pragma unroll
    for (int mi = 0; mi < 4; ++mi)
      af[mi] = *(const bf16x8*)((const char*)As +
               ((wr * 64 + mi * 16 + (lane & 15)) * 64 + (lane >> 4) * 16));
#pragma unroll
    for (int ni = 0; ni < 4; ++ni)
      bfr[ni] = *(const bf16x8*)((const char*)Bs +
               ((wc * 64 + ni * 16 + (lane & 15)) * 64 + (lane >> 4) * 16));
#pragma unroll
    for (int mi = 0; mi < 4; ++mi)
#pragma unroll
      for (int ni = 0; ni < 4; ++ni)
        acc[mi][ni] = __builtin_amdgcn_mfma_f32_16x16x32_bf16(af[mi], bfr[ni],
                                                              acc[mi][ni], 0, 0, 0);
    __syncthreads();
  }

  const float wp = *wpre, wa = *wadp;
  const float s = 2.f * wp + wa;
  const int crow = (lane >> 4) * 4;
  const int ccol = lane & 15;
#pragma unroll
  for (int mi = 0; mi < 4; ++mi)
#pragma unroll
    for (int ni = 0; ni < 4; ++ni) {
      int r0 = m0 + wr * 64 + mi * 16 + crow;
      int col = wc * 64 + ni * 16 + ccol;
      int cf = col & 63;
#pragma unroll
      for (int r = 0; r < 4; ++r) {
        int row = r0 + r;
        float g = acc[mi][ni][r];
        if (MODE == 0) {
          if (col < 64) {
            g += s * b0[cf];
            zbuf[(size_t)row * 64 + cf] = 1.f / (1.f + __expf(-g));
          } else {
            g += s * b1[cf];
            float rv = 1.f / (1.f + __expf(-g));
            rxout[(size_t)row * 64 + cf] = (__bf16)(rv * hid[(size_t)row * 64 + cf]);
          }
        } else {
          if (col < 64) {
            g += s * b0[cf];
            float cv = 1.f - 2.f / (1.f + __expf(2.f * g));
            float zv = zbuf[(size_t)row * 64 + cf];
            float hv = hid[(size_t)row * 64 + cf];
            outp[(size_t)row * 64 + cf] = (1.f - zv) * hv + zv * cv;
          }
        }
      }
    }
}

// ---------------------------------------------------------------------------
extern "C" void kernel_launch(void* const* d_in, const int* in_sizes, int n_in,
                              void* d_out, int out_size, void* d_ws, size_t ws_size,
                              hipStream_t stream) {
  (void)in_sizes; (void)n_in; (void)out_size;
  const float* x    = (const float*)d_in[0];
  const float* A1   = (const float*)d_in[1];
  const float* A2   = (const float*)d_in[2];
  const float* E1   = (const float*)d_in[3];
  const float* E2   = (const float*)d_in[4];
  const float* Wz   = (const float*)d_in[5];
  const float* bz   = (const float*)d_in[6];
  const float* Wr   = (const float*)d_in[7];
  const float* br   = (const float*)d_in[8];
  const float* Wc   = (const float*)d_in[9];
  const float* bc   = (const float*)d_in[10];
  const float* wpre = (const float*)d_in[11];
  const float* wadp = (const float*)d_in[12];
  float* out = (float*)d_out;

  char* ws = (char*)d_ws;
  const size_t NN2 = (size_t)NNODE * NNODE;  // 4,194,304 (= B*N*D too)
  __bf16* ADJ  = (__bf16*)(ws);                    // 6*NN2 bf16
  __bf16* XT   = (__bf16*)(ws + 6  * NN2 * 2);     // NN2
  __bf16* H1   = (__bf16*)(ws + 7  * NN2 * 2);     // 6*NN2
  __bf16* H2   = (__bf16*)(ws + 13 * NN2 * 2);     // 6*NN2
  __bf16* xbf  = (__bf16*)(ws + 19 * NN2 * 2);     // NN2
  __bf16* rx   = (__bf16*)(ws + 20 * NN2 * 2);     // NN2
  __bf16* S1   = (__bf16*)(ws + 21 * NN2 * 2);     // NN2
  __bf16* S2   = (__bf16*)(ws + 22 * NN2 * 2);     // NN2
  float*  zbuf = (float*)(ws + 23 * NN2 * 2);      // NN2 f32
  __bf16* Wzrt = (__bf16*)(ws + 23 * NN2 * 2 + NN2 * 4);
  __bf16* Wct  = (__bf16*)(ws + 23 * NN2 * 2 + NN2 * 4 + 128 * 192 * 2);
  if (ws_size < 23 * NN2 * 2 + NN2 * 4 + 2 * 128 * 192 * 2) return;

  // scratch reuse: SC lives in the (not-yet-used) H1 region, E1p/E2p in H2.
  __bf16* SC  = H1;                      // 4*NN2 bf16 scores
  __bf16* E1p = H2;                      // 4*2048*32 bf16
  __bf16* E2p = H2 + 4 * NNODE * 32;

  conv_bf16<<<4096, 256, 0, stream>>>(A1, ADJ);
  conv_bf16<<<4096, 256, 0, stream>>>(A2, ADJ + NN2);
  prep_e<<<128, 256, 0, stream>>>(E1, E2, E1p, E2p);
  score_gemm<<<dim3(16, 16, 4), 256, 0, stream>>>(E1p, E2p, SC);
  softmax_rows<<<2048, 256, 0, stream>>>(SC, ADJ + 2 * NN2);
  prep_w<<<96, 256, 0, stream>>>(Wz, Wr, Wc, wpre, wadp, Wzrt, Wct);
  transpose_x<<<dim3(32, 32), 256, 0, stream>>>(x, XT, xbf);

  // stage 1: hops on x (shared by z and r gates)
  gemm_hop<<<dim3(16, 16, 6), 256, 0, stream>>>(XT, 0, ADJ, H1);
  gemm_hop<<<dim3(16, 16, 6), 256, 0, stream>>>(H1, NN2, ADJ, H2);
  combine_s<<<dim3(32, 32), 256, 0, stream>>>(H1, H2, S1, S2, wpre, wadp);
  gemm_lin<0><<<512, 256, 0, stream>>>(xbf, S1, S2, Wzrt, bz, br, wpre, wadp,
                                       x, zbuf, rx, nullptr);

  // stage 2: hops on r*x
  transpose_rx<<<dim3(32, 32), 256, 0, stream>>>(rx, XT);
  gemm_hop<<<dim3(16, 16, 6), 256, 0, stream>>>(XT, 0, ADJ, H1);
  gemm_hop<<<dim3(16, 16, 6), 256, 0, stream>>>(H1, NN2, ADJ, H2);
  combine_s<<<dim3(32, 32), 256, 0, stream>>>(H1, H2, S1, S2, wpre, wadp);
  gemm_lin<1><<<512, 256, 0, stream>>>(rx, S1, S2, Wct, bc, nullptr, wpre, wadp,
                                       x, zbuf, nullptr, out);
}